// Round 1
// baseline (101.408 us; speedup 1.0000x reference)
//
#include <hip/hip_runtime.h>

#define DIM    256
#define NROWS  8192
#define NHALF  4096
#define NTILE  64                          // 8192 / 128 tiles per dim
#define NBLK   ((NTILE * (NTILE + 1)) / 2) // 2080 triangular tiles
#define RSTRIDE 128                        // z4 row stride in bytes (256 fp4)

using i32x4  = __attribute__((ext_vector_type(4))) int;
using i32x8  = __attribute__((ext_vector_type(8))) int;
using f32x16 = __attribute__((ext_vector_type(16))) float;

struct i32x8_pair { i32x4 lo, hi; };

// fp4 e2m1 RNE quantizer for pre-scaled input (representable {0,.5,1,1.5,2,3,4,6})
__device__ __forceinline__ unsigned fp4q(float v) {
  float a = fabsf(v);
  unsigned s = (__builtin_bit_cast(unsigned, v) >> 31) << 3;
  unsigned c = a < 0.25f ? 0u : a < 0.75f ? 1u : a < 1.25f ? 2u : a < 1.75f ? 3u
             : a < 2.50f ? 4u : a < 3.50f ? 5u : a < 5.00f ? 6u : 7u;
  return s | c;
}

// ---- kernel 1: row-normalize x (fp32) -> z4 (fp4 e2m1, x16 scale), 1 wave/row.
// Also re-zeroes the 32 banked fp64 accumulators + arrival counter every launch
// (workspace is poisoned between iterations; stream order publishes to gram_k).
__global__ __launch_bounds__(256) void normalize_k(const float* __restrict__ x,
                                                   unsigned char* __restrict__ z4,
                                                   double2* __restrict__ acc32,
                                                   unsigned int* __restrict__ cnt) {
  if (blockIdx.x == 0) {
    if (threadIdx.x < 32)       acc32[threadIdx.x] = make_double2(0.0, 0.0);
    else if (threadIdx.x == 32) *cnt = 0u;
  }
  const int row  = blockIdx.x * 4 + (threadIdx.x >> 6);
  const int lane = threadIdx.x & 63;
  float4 v = ((const float4*)(x + (size_t)row * DIM))[lane];
  float ss = v.x * v.x + v.y * v.y + v.z * v.z + v.w * v.w;
#pragma unroll
  for (int off = 32; off > 0; off >>= 1) ss += __shfl_xor(ss, off, 64);
  float rn = rsqrtf(fmaxf(ss, 1e-24f)) * 16.0f;   // pre-apply 2^4 (MX scale 2^-4)
  unsigned c0 = fp4q(v.x * rn), c1 = fp4q(v.y * rn);
  unsigned c2 = fp4q(v.z * rn), c3 = fp4q(v.w * rn);
  // element 2i in low nibble, 2i+1 in high nibble; lane covers elems 4l..4l+3
  unsigned short pk = (unsigned short)((c0 | (c1 << 4)) | ((c2 | (c3 << 4)) << 8));
  ((unsigned short*)(z4 + (size_t)row * RSTRIDE))[lane] = pk;
}

// ---- kernel 2: Gram exp-sum over upper-triangular 128x128 tiles, MX-fp4.
// Full K=256 staged in ONE round (A+B = 32 KB -> 4 blocks/CU, one barrier).
// Final reduction folded in: banked f64 atomics + last-arriving-block finalize
// (replaces the former reduce_k launch).
__global__ __launch_bounds__(256, 4) void gram_k(const unsigned char* __restrict__ z4,
                                                 double2* __restrict__ acc32,
                                                 unsigned int* __restrict__ cnt,
                                                 float* __restrict__ out) {
  __shared__ unsigned char As[128 * RSTRIDE];   // 16 KB
  __shared__ unsigned char Bs[128 * RSTRIDE];   // 16 KB
  __shared__ float red[8];
  __shared__ int lastf;

  // linear block id -> (bi, bj), bi <= bj
  const int bid = blockIdx.x;
  int bi = (int)((129.0 - sqrt(129.0 * 129.0 - 8.0 * (double)bid)) * 0.5);
  while ((bi * (129 - bi)) / 2 > bid) --bi;
  while (((bi + 1) * (128 - bi)) / 2 <= bid) ++bi;
  const int bj = bi + (bid - (bi * (129 - bi)) / 2);

  const int tid   = threadIdx.x;
  const int lane  = tid & 63;
  const int w     = tid >> 6;
  const int wr    = w >> 1, wc = w & 1;     // 2x2 wave grid, 64x64 each
  const int l31   = lane & 31;
  const int khalf = lane >> 5;              // K-half selector for 32x32 frags

  const size_t rowA0 = (size_t)bi * 128;
  const size_t rowB0 = (size_t)bj * 128;

  // stage 128 rows x 128 B (fp4) for A and B via global_load_lds, 16B/lane.
  // LDS 16B-chunk cb holds global chunk cb ^ (row&7) (swizzle applied on the
  // global side: glds dest = wave-uniform base + lane*16). 8 chunks/row.
#pragma unroll
  for (int i = 0; i < 4; ++i) {
    int c   = i * 256 + tid;                // 0..1023 -> (row, chunk)
    int row = c >> 3;                       // 0..127
    int cb  = c & 7;
    int gcb = cb ^ (row & 7);
    const unsigned char* ga = z4 + (rowA0 + row) * RSTRIDE + gcb * 16;
    const unsigned char* gb = z4 + (rowB0 + row) * RSTRIDE + gcb * 16;
    __builtin_amdgcn_global_load_lds(
        (const __attribute__((address_space(1))) void*)ga,
        (__attribute__((address_space(3))) void*)&As[(size_t)(i * 256 + (tid & ~63)) * 16],
        16, 0, 0);
    __builtin_amdgcn_global_load_lds(
        (const __attribute__((address_space(1))) void*)gb,
        (__attribute__((address_space(3))) void*)&Bs[(size_t)(i * 256 + (tid & ~63)) * 16],
        16, 0, 0);
  }
  __syncthreads();                          // the only staging barrier

  f32x16 acc_f[2][2] = {};
  const i32x4 zero4 = {0, 0, 0, 0};
#pragma unroll
  for (int kc = 0; kc < 4; ++kc) {          // four K=64 MFMA chunks
    // fp4: each lane's 32 K-elements = ONE 16B chunk; chunk id = kc*2 + khalf
    const int ch = kc * 2 + khalf;
    i32x8 a[2], b[2];
#pragma unroll
    for (int t = 0; t < 2; ++t) {
      int mr = wr * 64 + t * 32 + l31;
      i32x8_pair pa = { *(const i32x4*)&As[mr * RSTRIDE + (ch ^ (mr & 7)) * 16], zero4 };
      a[t] = __builtin_bit_cast(i32x8, pa); // fp4 reads only low 4 regs
      int nr = wc * 64 + t * 32 + l31;
      i32x8_pair pb = { *(const i32x4*)&Bs[nr * RSTRIDE + (ch ^ (nr & 7)) * 16], zero4 };
      b[t] = __builtin_bit_cast(i32x8, pb);
    }
#pragma unroll
    for (int ti = 0; ti < 2; ++ti)
#pragma unroll
      for (int tj = 0; tj < 2; ++tj)
        acc_f[ti][tj] = __builtin_amdgcn_mfma_scale_f32_32x32x64_f8f6f4(
            a[ti], b[tj], acc_f[ti][tj],
            4, 4,                           // FMT: fp4 e2m1 A and B
            0, 0x7B7B7B7B,                  // scale_a = 2^-4 (E8M0 123)
            0, 0x7B7B7B7B);                 // scale_b = 2^-4
  }

  // epilogue: exp(cos/TEMP), TEMP = 2. Uniform-branch diagonal handling.
  const bool tdiag = (bi == bj);            // true diagonal tile
  const bool sdiag = (bj == bi + 32);       // (i, i+4096) sim_s tile
  float lsum = 0.0f, dsum = 0.0f;
  if (tdiag || sdiag) {
#pragma unroll
    for (int ti = 0; ti < 2; ++ti)
#pragma unroll
      for (int tj = 0; tj < 2; ++tj)
#pragma unroll
        for (int r = 0; r < 16; ++r) {
          float e = __expf(acc_f[ti][tj][r] * 0.5f);
          lsum += e;
          // 32x32 C/D: col = lane&31, row = (reg&3) + 8*(reg>>2) + 4*khalf
          int row_l = (r & 3) + 8 * (r >> 2) + 4 * khalf;
          if (wr == wc && ti == tj && row_l == l31) dsum += e;
        }
  } else {
#pragma unroll
    for (int ti = 0; ti < 2; ++ti)
#pragma unroll
      for (int tj = 0; tj < 2; ++tj)
#pragma unroll
        for (int r = 0; r < 16; ++r)
          lsum += __expf(acc_f[ti][tj][r] * 0.5f);
  }
#pragma unroll
  for (int off = 32; off > 0; off >>= 1) lsum += __shfl_xor(lsum, off, 64);
  if (tdiag || sdiag) {
#pragma unroll
    for (int off = 32; off > 0; off >>= 1) dsum += __shfl_xor(dsum, off, 64);
  }
  if (lane == 0) { red[w] = lsum; red[4 + w] = dsum; }
  __syncthreads();

  if (tid == 0) {
    float l  = red[0] + red[1] + red[2] + red[3];
    float dd = red[4] + red[5] + red[6] + red[7];
    // S accumulates T_full + all_diag: diag tile contributes lsum + diag
    // extra, off-diag tile counts twice by symmetry.
    double vx = tdiag ? (double)l + (double)dd : 2.0 * (double)l;
    atomicAdd(&acc32[bid & 31].x, vx);      // banked: <=65 adds/slot, hidden
    if (sdiag) atomicAdd(&acc32[bid & 31].y, (double)dd);
    // release our adds, then count arrival (agent scope covers cross-XCD)
    unsigned int old = __hip_atomic_fetch_add(cnt, 1u, __ATOMIC_ACQ_REL,
                                              __HIP_MEMORY_SCOPE_AGENT);
    lastf = (old == NBLK - 1);
  }
  __syncthreads();

  // last-arriving block: fold 32 banks and emit the loss (replaces reduce_k)
  if (lastf && tid < 32) {
    double s = __hip_atomic_load(&acc32[tid].x, __ATOMIC_RELAXED,
                                 __HIP_MEMORY_SCOPE_AGENT);
    double d = __hip_atomic_load(&acc32[tid].y, __ATOMIC_RELAXED,
                                 __HIP_MEMORY_SCOPE_AGENT);
#pragma unroll
    for (int off = 16; off > 0; off >>= 1) {
      s += __shfl_down(s, off, 64);
      d += __shfl_down(d, off, 64);
    }
    if (tid == 0) out[0] = (float)(log(0.5 * s + d) - log(d));
  }
}

extern "C" void kernel_launch(void* const* d_in, const int* in_sizes, int n_in,
                              void* d_out, int out_size, void* d_ws, size_t ws_size,
                              hipStream_t stream) {
  const float* x    = (const float*)d_in[0];
  unsigned char* z4 = (unsigned char*)d_ws;                  // 8192*128 B = 1 MB
  double2* acc32    = (double2*)((char*)d_ws + (size_t)NROWS * RSTRIDE); // 512 B
  unsigned int* cnt = (unsigned int*)((char*)d_ws + (size_t)NROWS * RSTRIDE
                                      + 32 * sizeof(double2));
  float* out        = (float*)d_out;

  normalize_k<<<dim3(NROWS / 4), dim3(256), 0, stream>>>(x, z4, acc32, cnt);
  gram_k<<<dim3(NBLK), dim3(256), 0, stream>>>(z4, acc32, cnt, out);
}

// Round 3
// 77.511 us; speedup vs baseline: 1.3083x; 1.3083x over previous
//
#include <hip/hip_runtime.h>

#define DIM    256
#define NROWS  8192
#define NTILE  64                          // 8192 / 128 tiles per dim
#define NBLK   ((NTILE * (NTILE + 1)) / 2) // 2080 triangular tiles
#define NB     512                         // gram grid: exactly 2 blocks/CU
#define NPART  (NB * 4)                    // one double2 per wave
#define RSTRIDE 128                        // z4 row stride in bytes (256 fp4)

using i32x4  = __attribute__((ext_vector_type(4))) int;
using i32x8  = __attribute__((ext_vector_type(8))) int;
using f32x16 = __attribute__((ext_vector_type(16))) float;

struct i32x8_pair { i32x4 lo, hi; };

// fp4 e2m1 RNE quantizer for pre-scaled input (representable {0,.5,1,1.5,2,3,4,6})
__device__ __forceinline__ unsigned fp4q(float v) {
  float a = fabsf(v);
  unsigned s = (__builtin_bit_cast(unsigned, v) >> 31) << 3;
  unsigned c = a < 0.25f ? 0u : a < 0.75f ? 1u : a < 1.25f ? 2u : a < 1.75f ? 3u
             : a < 2.50f ? 4u : a < 3.50f ? 5u : a < 5.00f ? 6u : 7u;
  return s | c;
}

// linear triangular tile id -> (bi, bj), bi <= bj  (verified for all 2080 ids)
__device__ __forceinline__ void tile_rc(int t, int& bi, int& bj) {
  int i = (int)((129.0 - sqrt(129.0 * 129.0 - 8.0 * (double)t)) * 0.5);
  while ((i * (129 - i)) / 2 > t) --i;
  while (((i + 1) * (128 - i)) / 2 <= t) ++i;
  bi = i;
  bj = i + (t - (i * (129 - i)) / 2);
}

// ---- kernel 1: row-normalize x (fp32) -> z4 (fp4 e2m1, x16 scale), 1 wave/row.
__global__ __launch_bounds__(256) void normalize_k(const float* __restrict__ x,
                                                   unsigned char* __restrict__ z4) {
  const int row  = blockIdx.x * 4 + (threadIdx.x >> 6);
  const int lane = threadIdx.x & 63;
  float4 v = ((const float4*)(x + (size_t)row * DIM))[lane];
  float ss = v.x * v.x + v.y * v.y + v.z * v.z + v.w * v.w;
#pragma unroll
  for (int off = 32; off > 0; off >>= 1) ss += __shfl_xor(ss, off, 64);
  float rn = rsqrtf(fmaxf(ss, 1e-24f)) * 16.0f;   // pre-apply 2^4 (MX scale 2^-4)
  unsigned c0 = fp4q(v.x * rn), c1 = fp4q(v.y * rn);
  unsigned c2 = fp4q(v.z * rn), c3 = fp4q(v.w * rn);
  // element 2i in low nibble, 2i+1 in high nibble; lane covers elems 4l..4l+3
  unsigned short pk = (unsigned short)((c0 | (c1 << 4)) | ((c2 | (c3 << 4)) << 8));
  ((unsigned short*)(z4 + (size_t)row * RSTRIDE))[lane] = pk;
}

// ---- kernel 2: Gram exp-sum over upper-triangular 128x128 tiles, MX-fp4.
// 512 blocks (2/CU co-resident), tiles grid-strided: block b does tiles
// b, b+512, b+1024, b+1536 (+ b+2048 for b<32). A+B double-buffered (exactly
// 64 KB LDS). Stage for tile k+2 issued during tile k; counted vmcnt(8) keeps
// the next tile's loads in flight across raw s_barriers (no vmcnt(0) drain in
// steady state). Per-LANE f64 accumulation; one plain store per wave at exit.
__global__ __launch_bounds__(256, 2) void gram_k(const unsigned char* __restrict__ z4,
                                                 double2* __restrict__ partial) {
  __shared__ unsigned char As[2][128 * RSTRIDE];   // 2 x 16 KB
  __shared__ unsigned char Bs[2][128 * RSTRIDE];   // 2 x 16 KB  (total = 64 KB)

  const int tid   = threadIdx.x;
  const int lane  = tid & 63;
  const int w     = tid >> 6;
  const int wr    = w >> 1, wc = w & 1;     // 2x2 wave grid, 64x64 each
  const int l31   = lane & 31;
  const int khalf = lane >> 5;              // K-half selector for 32x32 frags

  const int b  = blockIdx.x;
  const int nt = 4 + (b < (NBLK - 4 * NB) ? 1 : 0);   // 32 blocks get a 5th tile

  // stage 128 rows x 128 B (fp4) for A and B of tile t into buffer s.
  // LDS 16B-chunk cb holds global chunk cb ^ (row&7) (swizzle on global side;
  // glds dest = wave-uniform base + lane*16). 8 glds per wave per call.
  auto stage = [&](int s, int t) {
    int sbi, sbj; tile_rc(t, sbi, sbj);
    const size_t rA = (size_t)sbi * 128, rB = (size_t)sbj * 128;
#pragma unroll
    for (int i = 0; i < 4; ++i) {
      int c   = i * 256 + tid;              // 0..1023 -> (row, chunk)
      int row = c >> 3;                     // 0..127
      int cb  = c & 7;
      int gcb = cb ^ (row & 7);
      const unsigned char* ga = z4 + (rA + row) * RSTRIDE + gcb * 16;
      const unsigned char* gb = z4 + (rB + row) * RSTRIDE + gcb * 16;
      __builtin_amdgcn_global_load_lds(
          (const __attribute__((address_space(1))) void*)ga,
          (__attribute__((address_space(3))) void*)&As[s][(size_t)(i * 256 + (tid & ~63)) * 16],
          16, 0, 0);
      __builtin_amdgcn_global_load_lds(
          (const __attribute__((address_space(1))) void*)gb,
          (__attribute__((address_space(3))) void*)&Bs[s][(size_t)(i * 256 + (tid & ~63)) * 16],
          16, 0, 0);
    }
  };

  // prologue: fill both pipeline slots; wait only for slot 0 (vmcnt(8) leaves
  // slot 1's 8 glds in flight), then publish.
  stage(0, b);
  stage(1, b + NB);
  asm volatile("s_waitcnt vmcnt(8)" ::: "memory");
  __builtin_amdgcn_s_barrier();
  __builtin_amdgcn_sched_barrier(0);

  double accS = 0.0, accD = 0.0;
  const i32x4 zero4 = {0, 0, 0, 0};

  for (int k = 0; ; ++k) {
    const int cur = k & 1;
    int bik, bjk; tile_rc(b + k * NB, bik, bjk);

    f32x16 acc_f[2][2] = {};
#pragma unroll
    for (int kc = 0; kc < 4; ++kc) {        // four K=64 MFMA chunks
      // fp4: each lane's 32 K-elements = ONE 16B chunk; chunk id = kc*2+khalf
      const int ch = kc * 2 + khalf;
      i32x8 a[2], bf[2];
#pragma unroll
      for (int t = 0; t < 2; ++t) {
        int mr = wr * 64 + t * 32 + l31;
        i32x8_pair pa = { *(const i32x4*)&As[cur][mr * RSTRIDE + (ch ^ (mr & 7)) * 16], zero4 };
        a[t] = __builtin_bit_cast(i32x8, pa);  // fp4 reads only low 4 regs
        int nr = wc * 64 + t * 32 + l31;
        i32x8_pair pb = { *(const i32x4*)&Bs[cur][nr * RSTRIDE + (ch ^ (nr & 7)) * 16], zero4 };
        bf[t] = __builtin_bit_cast(i32x8, pb);
      }
#pragma unroll
      for (int ti = 0; ti < 2; ++ti)
#pragma unroll
        for (int tj = 0; tj < 2; ++tj)
          acc_f[ti][tj] = __builtin_amdgcn_mfma_scale_f32_32x32x64_f8f6f4(
              a[ti], bf[tj], acc_f[ti][tj],
              4, 4,                         // FMT: fp4 e2m1 A and B
              0, 0x7B7B7B7B,                // scale_a = 2^-4 (E8M0 123)
              0, 0x7B7B7B7B);               // scale_b = 2^-4
    }

    // epilogue: exp(cos/TEMP), TEMP = 2. Uniform-branch diagonal handling.
    const bool tdiag = (bik == bjk);        // true diagonal tile
    const bool sdiag = (bjk == bik + 32);   // (i, i+4096) sim_s tile
    float lsum = 0.0f, dsum = 0.0f;
    if (tdiag || sdiag) {
#pragma unroll
      for (int ti = 0; ti < 2; ++ti)
#pragma unroll
        for (int tj = 0; tj < 2; ++tj)
#pragma unroll
          for (int r = 0; r < 16; ++r) {
            float e = __expf(acc_f[ti][tj][r] * 0.5f);
            lsum += e;
            // 32x32 C/D: col = lane&31, row = (reg&3) + 8*(reg>>2) + 4*khalf
            int row_l = (r & 3) + 8 * (r >> 2) + 4 * khalf;
            if (wr == wc && ti == tj && row_l == l31) dsum += e;
          }
    } else {
#pragma unroll
      for (int ti = 0; ti < 2; ++ti)
#pragma unroll
        for (int tj = 0; tj < 2; ++tj)
#pragma unroll
          for (int r = 0; r < 16; ++r)
            lsum += __expf(acc_f[ti][tj][r] * 0.5f);
    }
    // per-LANE tile contribution (linear in lanes: summing later gives the
    // tile totals). diag tile contributes lsum + diag extra; off-diag twice.
    accS += tdiag ? (double)lsum + (double)dsum : 2.0 * (double)lsum;
    if (sdiag) accD += (double)dsum;

    if (k == nt - 1) break;

    // barrier A: all waves done reading buf[cur] (own lgkm already drained by
    // MFMA-use waits); safe to restage it.
    __builtin_amdgcn_s_barrier();
    __builtin_amdgcn_sched_barrier(0);
    if (k + 2 < nt) {
      stage(cur, b + (k + 2) * NB);          // refill consumed buffer
      asm volatile("s_waitcnt vmcnt(8)" ::: "memory");  // tile k+1's 8 landed
    } else {
      asm volatile("s_waitcnt vmcnt(0)" ::: "memory");  // drain: last buffer
    }
    __builtin_amdgcn_s_barrier();            // barrier B: buf[cur^1] staged
    __builtin_amdgcn_sched_barrier(0);
  }

  // cross-lane f64 reduce within each wave; one plain store per wave.
#pragma unroll
  for (int off = 32; off > 0; off >>= 1) {
    accS += __shfl_xor(accS, off, 64);
    accD += __shfl_xor(accD, off, 64);
  }
  if (lane == 0) {
    double2 v; v.x = accS; v.y = accD;
    partial[b * 4 + w] = v;                 // unique slot: no RMW, no init
  }
}

// ---- kernel 3: reduce 2048 partials, compute the loss. One block.
__global__ __launch_bounds__(256) void reduce_k(const double2* __restrict__ partial,
                                               float* __restrict__ out) {
  __shared__ double redS[4], redD[4];
  double s = 0.0, ss = 0.0;
  for (int i = threadIdx.x; i < NPART; i += 256) {
    double2 v = partial[i];
    s += v.x; ss += v.y;
  }
#pragma unroll
  for (int off = 32; off > 0; off >>= 1) {
    s  += __shfl_xor(s,  off, 64);
    ss += __shfl_xor(ss, off, 64);
  }
  const int w = threadIdx.x >> 6;
  if ((threadIdx.x & 63) == 0) { redS[w] = s; redD[w] = ss; }
  __syncthreads();
  if (threadIdx.x == 0) {
    double S  = redS[0] + redS[1] + redS[2] + redS[3];
    double sd = redD[0] + redD[1] + redD[2] + redD[3];
    out[0] = (float)(log(0.5 * S + sd) - log(sd));
  }
}

extern "C" void kernel_launch(void* const* d_in, const int* in_sizes, int n_in,
                              void* d_out, int out_size, void* d_ws, size_t ws_size,
                              hipStream_t stream) {
  const float* x    = (const float*)d_in[0];
  unsigned char* z4 = (unsigned char*)d_ws;                  // 8192*128 B = 1 MB
  double2* partial  = (double2*)((char*)d_ws + (size_t)NROWS * RSTRIDE);  // 2048*16 B
  float* out        = (float*)d_out;

  normalize_k<<<dim3(NROWS / 4), dim3(256), 0, stream>>>(x, z4);
  gram_k<<<dim3(NB), dim3(256), 0, stream>>>(z4, partial);
  reduce_k<<<dim3(1), dim3(256), 0, stream>>>(partial, out);
}

// Round 4
// 74.382 us; speedup vs baseline: 1.3634x; 1.0421x over previous
//
#include <hip/hip_runtime.h>

#define DIM     256
#define NROWS   8192
#define NTILE   64                           // 8192 / 128 tiles per dim
#define NBLK    ((NTILE * (NTILE + 1)) / 2)  // 2080 triangular tiles
#define CHPLANE ((size_t)NROWS * 16)         // chunk-major plane stride in bytes

using i32x4  = __attribute__((ext_vector_type(4))) int;
using i32x8  = __attribute__((ext_vector_type(8))) int;
using f32x16 = __attribute__((ext_vector_type(16))) float;

struct i32x8_pair { i32x4 lo, hi; };

// fp4 e2m1 RNE quantizer for pre-scaled input (representable {0,.5,1,1.5,2,3,4,6})
__device__ __forceinline__ unsigned fp4q(float v) {
  float a = fabsf(v);
  unsigned s = (__builtin_bit_cast(unsigned, v) >> 31) << 3;
  unsigned c = a < 0.25f ? 0u : a < 0.75f ? 1u : a < 1.25f ? 2u : a < 1.75f ? 3u
             : a < 2.50f ? 4u : a < 3.50f ? 5u : a < 5.00f ? 6u : 7u;
  return s | c;
}

// linear triangular tile id -> (bi, bj), bi <= bj
__device__ __forceinline__ void tile_rc(int t, int& bi, int& bj) {
  int i = (int)((129.0 - sqrt(129.0 * 129.0 - 8.0 * (double)t)) * 0.5);
  while ((i * (129 - i)) / 2 > t) --i;
  while (((i + 1) * (128 - i)) / 2 <= t) ++i;
  bi = i;
  bj = i + (t - (i * (129 - i)) / 2);
}

// e^(x/2) = 2^(x * log2(e)/2): one v_mul + one v_exp_f32 (folds the /TEMP)
__device__ __forceinline__ float exp_half(float x) {
  float t = x * 0.7213475204444817f;
  float r;
  asm("v_exp_f32 %0, %1" : "=v"(r) : "v"(t));
  return r;
}

// ---- kernel 1: row-normalize x (fp32) -> z4 (fp4 e2m1, x16 scale), 1 wave/row.
// z4 is CHUNK-MAJOR: z4[chunk][row] with 16B per (chunk,row); plane = 128 KB.
// This makes gram's per-lane fragment gathers perfectly coalesced (512B runs).
__global__ __launch_bounds__(256) void normalize_k(const float* __restrict__ x,
                                                   unsigned char* __restrict__ z4) {
  const int row  = blockIdx.x * 4 + (threadIdx.x >> 6);
  const int lane = threadIdx.x & 63;
  float4 v = ((const float4*)(x + (size_t)row * DIM))[lane];
  float ss = v.x * v.x + v.y * v.y + v.z * v.z + v.w * v.w;
#pragma unroll
  for (int off = 32; off > 0; off >>= 1) ss += __shfl_xor(ss, off, 64);
  float rn = rsqrtf(fmaxf(ss, 1e-24f)) * 16.0f;   // pre-apply 2^4 (MX scale 2^-4)
  unsigned c0 = fp4q(v.x * rn), c1 = fp4q(v.y * rn);
  unsigned c2 = fp4q(v.z * rn), c3 = fp4q(v.w * rn);
  // element 2i in low nibble, 2i+1 in high nibble; lane covers elems 4l..4l+3
  unsigned short pk = (unsigned short)((c0 | (c1 << 4)) | ((c2 | (c3 << 4)) << 8));
  // lane's 2 bytes land in chunk (lane>>3), byte-in-chunk (2*lane)&15
  *(unsigned short*)(z4 + (size_t)(lane >> 3) * CHPLANE
                        + (size_t)row * 16 + ((2 * lane) & 14)) = pk;
}

// ---- kernel 2: Gram exp-sum over upper-triangular 128x128 tiles, MX-fp4.
// NO LDS staging (z4 = 1 MB is L2-resident; staging was pure overhead): each
// lane loads its MFMA fragments (16B = one 32-elem K-chunk of one row)
// directly from global. Chunk-major layout -> every load is two contiguous
// 512B segments. No barriers in the hot path; waves fully independent;
// latency hidden by TLP (3 waves/SIMD, VGPR-bound).
__global__ __launch_bounds__(256, 3) void gram_k(const unsigned char* __restrict__ z4,
                                                 double2* __restrict__ partial) {
  __shared__ float red[8];

  const int tid   = threadIdx.x;
  const int lane  = tid & 63;
  const int w     = tid >> 6;
  const int wr    = w >> 1, wc = w & 1;     // 2x2 wave grid, 64x64 each
  const int l31   = lane & 31;
  const int khalf = lane >> 5;              // K-half selector for 32x32 frags

  int bi, bj; tile_rc(blockIdx.x, bi, bj);

  // lane base addresses: chunk plane (kc*2 + khalf), row = tile_row0 + sub
  const unsigned char* baseA = z4 + (size_t)khalf * CHPLANE
                             + ((size_t)bi * 128 + wr * 64 + l31) * 16;
  const unsigned char* baseB = z4 + (size_t)khalf * CHPLANE
                             + ((size_t)bj * 128 + wc * 64 + l31) * 16;

  f32x16 acc_f[2][2] = {};
  const i32x4 zero4 = {0, 0, 0, 0};
#pragma unroll
  for (int kc = 0; kc < 4; ++kc) {          // four K=64 MFMA chunks
    i32x8 a[2], b[2];
#pragma unroll
    for (int t = 0; t < 2; ++t) {
      i32x8_pair pa = { *(const i32x4*)(baseA + (size_t)(2 * kc) * CHPLANE + t * 32 * 16),
                        zero4 };
      a[t] = __builtin_bit_cast(i32x8, pa); // fp4 reads only low 4 regs
      i32x8_pair pb = { *(const i32x4*)(baseB + (size_t)(2 * kc) * CHPLANE + t * 32 * 16),
                        zero4 };
      b[t] = __builtin_bit_cast(i32x8, pb);
    }
#pragma unroll
    for (int ti = 0; ti < 2; ++ti)
#pragma unroll
      for (int tj = 0; tj < 2; ++tj)
        acc_f[ti][tj] = __builtin_amdgcn_mfma_scale_f32_32x32x64_f8f6f4(
            a[ti], b[tj], acc_f[ti][tj],
            4, 4,                           // FMT: fp4 e2m1 A and B
            0, 0x7B7B7B7B,                  // scale_a = 2^-4 (E8M0 123)
            0, 0x7B7B7B7B);                 // scale_b = 2^-4
  }

  // epilogue: exp(cos/TEMP), TEMP = 2. Uniform-branch diagonal handling.
  const bool tdiag = (bi == bj);            // true diagonal tile
  const bool sdiag = (bj == bi + 32);       // (i, i+4096) sim_s tile
  float lsum = 0.0f, dsum = 0.0f;
  if (tdiag || sdiag) {
#pragma unroll
    for (int ti = 0; ti < 2; ++ti)
#pragma unroll
      for (int tj = 0; tj < 2; ++tj)
#pragma unroll
        for (int r = 0; r < 16; ++r) {
          float e = exp_half(acc_f[ti][tj][r]);
          lsum += e;
          // 32x32 C/D: col = lane&31, row = (reg&3) + 8*(reg>>2) + 4*khalf
          int row_l = (r & 3) + 8 * (r >> 2) + 4 * khalf;
          if (wr == wc && ti == tj && row_l == l31) dsum += e;
        }
  } else {
#pragma unroll
    for (int ti = 0; ti < 2; ++ti)
#pragma unroll
      for (int tj = 0; tj < 2; ++tj)
#pragma unroll
        for (int r = 0; r < 16; ++r)
          lsum += exp_half(acc_f[ti][tj][r]);
  }
#pragma unroll
  for (int off = 32; off > 0; off >>= 1) lsum += __shfl_xor(lsum, off, 64);
  if (tdiag || sdiag) {
#pragma unroll
    for (int off = 32; off > 0; off >>= 1) dsum += __shfl_xor(dsum, off, 64);
  }
  if (lane == 0) { red[w] = lsum; red[4 + w] = dsum; }
  __syncthreads();                          // only barrier: final combine

  if (tid == 0) {
    float l  = red[0] + red[1] + red[2] + red[3];
    float dd = red[4] + red[5] + red[6] + red[7];
    // diag tile contributes lsum + diag extra; off-diag counts twice (symmetry)
    double2 v;
    v.x = tdiag ? (double)l + (double)dd : 2.0 * (double)l;
    v.y = sdiag ? (double)dd : 0.0;
    partial[blockIdx.x] = v;                // unique slot: plain store, no RMW
  }
}

// ---- kernel 3: reduce 2080 partials, compute the loss. One block.
__global__ __launch_bounds__(256) void reduce_k(const double2* __restrict__ partial,
                                               float* __restrict__ out) {
  __shared__ double redS[4], redD[4];
  double s = 0.0, ss = 0.0;
  for (int i = threadIdx.x; i < NBLK; i += 256) {
    double2 v = partial[i];
    s += v.x; ss += v.y;
  }
#pragma unroll
  for (int off = 32; off > 0; off >>= 1) {
    s  += __shfl_xor(s,  off, 64);
    ss += __shfl_xor(ss, off, 64);
  }
  const int w = threadIdx.x >> 6;
  if ((threadIdx.x & 63) == 0) { redS[w] = s; redD[w] = ss; }
  __syncthreads();
  if (threadIdx.x == 0) {
    double S  = redS[0] + redS[1] + redS[2] + redS[3];
    double sd = redD[0] + redD[1] + redD[2] + redD[3];
    out[0] = (float)(log(0.5 * S + sd) - log(sd));
  }
}

extern "C" void kernel_launch(void* const* d_in, const int* in_sizes, int n_in,
                              void* d_out, int out_size, void* d_ws, size_t ws_size,
                              hipStream_t stream) {
  const float* x    = (const float*)d_in[0];
  unsigned char* z4 = (unsigned char*)d_ws;                  // 8 chunk planes = 1 MB
  double2* partial  = (double2*)((char*)d_ws + 8 * CHPLANE); // 2080*16 B
  float* out        = (float*)d_out;

  normalize_k<<<dim3(NROWS / 4), dim3(256), 0, stream>>>(x, z4);
  gram_k<<<dim3(NBLK), dim3(256), 0, stream>>>(z4, partial);
  reduce_k<<<dim3(1), dim3(256), 0, stream>>>(partial, out);
}